// Round 6
// baseline (1381.567 us; speedup 1.0000x reference)
//
#include <hip/hip_runtime.h>

#define BATCH 4
#define NPTS  4096
#define NC    1024
#define KNN   32
#define CIN   128
#define CO    256
#define DP    136   // padded feature dim (max over types); pad entries are exact zeros

// output layout (flat f32, reference return order)
#define OFF_CXYZ 0
#define OFF_CMAD (BATCH*NC*3)
#define OFF_CADJ (OFF_CMAD + BATCH*NC*3)
#define OFF_CPT  (OFF_CADJ + BATCH*NC*2)
#define OFF_OMAD (OFF_CPT  + BATCH*NC*4)
#define OFF_OADJ (OFF_OMAD + BATCH*NC*CO)
#define OFF_OPT  (OFF_OADJ + BATCH*NC*CO)
#define OFF_OCST (OFF_OPT  + BATCH*NC*CO)

typedef unsigned long long u64;

// ---------------------------------------------------------------------------
// u64 wave-64 reduce via DPP (VALU pipe). Result valid in lane 63.
// ---------------------------------------------------------------------------
template<bool MAXI>
__device__ __forceinline__ u64 wave_red_u64(u64 k)
{
    const int oldv = MAXI ? 0 : -1;
#define DPP_STEP(C)                                                              \
    {                                                                            \
        unsigned plo = (unsigned)__builtin_amdgcn_update_dpp(oldv, (int)(unsigned)k,        C, 0xf, 0xf, false); \
        unsigned phi = (unsigned)__builtin_amdgcn_update_dpp(oldv, (int)(unsigned)(k>>32),  C, 0xf, 0xf, false); \
        u64 p = ((u64)phi << 32) | plo;                                          \
        if (MAXI ? (p > k) : (p < k)) k = p;                                     \
    }
    DPP_STEP(0x111) DPP_STEP(0x112) DPP_STEP(0x114)
    DPP_STEP(0x118) DPP_STEP(0x142) DPP_STEP(0x143)
#undef DPP_STEP
    return k;
}

// ---------------------------------------------------------------------------
// Standalone prep kernel (runs BEFORE the mega kernel; the kernel boundary
// gives full coherence for the plain-load M/Wvp reads in the attn role).
// ---------------------------------------------------------------------------
__global__ __launch_bounds__(256) void prep_kernel(
    const float* __restrict__ wq_mad, const float* __restrict__ wk_mad, const float* __restrict__ wv_mad,
    const float* __restrict__ wq_adj, const float* __restrict__ wk_adj, const float* __restrict__ wv_adj,
    const float* __restrict__ wq_pt,  const float* __restrict__ wk_pt,  const float* __restrict__ wv_pt,
    const float* __restrict__ wq_cst, const float* __restrict__ wk_cst, const float* __restrict__ wv_cst,
    float* __restrict__ M, float* __restrict__ Wvp)
{
    __shared__ float sq[CO];
    const int t = threadIdx.x;
    const int r    = blockIdx.x;          // 0..4*DP-1
    const int type = r / DP;
    const int row  = r - type * DP;
    const float* wq; const float* wk; const float* wv; int D;
    if (type == 0)      { wq=wq_mad; wk=wk_mad; wv=wv_mad; D=131; }
    else if (type == 1) { wq=wq_adj; wk=wk_adj; wv=wv_adj; D=132; }
    else if (type == 2) { wq=wq_pt;  wk=wk_pt;  wv=wv_pt;  D=136; }
    else                { wq=wq_cst; wk=wk_cst; wv=wv_cst; D=131; }

    Wvp[((size_t)type*DP + row)*CO + t] = (row < D) ? wv[(size_t)row*CO + t] : 0.f;

    if (row < CIN) {
        sq[t] = wq[(size_t)row*CO + t];
        __syncthreads();
        if (t < DP) {
            float acc = 0.f;
            if (t < D) {
                const float* wkr = wk + (size_t)t * CO;
                for (int h = 0; h < CO; h += 4) {
                    float4 a = *(const float4*)&wkr[h];
                    float4 b4 = *(const float4*)&sq[h];
                    acc = fmaf(a.x,b4.x,acc); acc = fmaf(a.y,b4.y,acc);
                    acc = fmaf(a.z,b4.z,acc); acc = fmaf(a.w,b4.w,acc);
                }
            }
            M[((size_t)type*CIN + row)*DP + t] = acc;
        }
    }
}

// ---------------------------------------------------------------------------
// FPS role (round-5 verified math; per-step relaxed agent publish so knn can
// consume progressively). s_setprio(1): the co-resident worker block soaks
// only FPS's stall slots, not its issue slots.
// ---------------------------------------------------------------------------
__device__ __forceinline__ void fps_role(int b, const float* __restrict__ xyz,
                                         int* __restrict__ fps_idx, char* s_raw)
{
    float4* s_xyz  = (float4*)s_raw;                   // 64 KB
    u64 (*s_ck)[4] = (u64(*)[4])(s_raw + 65536);       // 64 B
    const int t = threadIdx.x;
    const float* xb = xyz + (size_t)b * NPTS * 3;

    __builtin_amdgcn_s_setprio(1);

    float px[16], py[16], pz[16], dd[16];
#pragma unroll
    for (int i = 0; i < 16; ++i) {
        int p = t + i * 256;
        px[i] = xb[p*3+0]; py[i] = xb[p*3+1]; pz[i] = xb[p*3+2];
        s_xyz[p] = make_float4(px[i], py[i], pz[i], 0.f);
        dd[i] = 1e10f;
    }
    __syncthreads();

    int far = 0;
    float cx = xb[0], cy = xb[1], cz = xb[2];
    for (int s = 0; s < NC; ++s) {
        if (t == 0)
            __hip_atomic_store(&fps_idx[(b<<10) + s], far, __ATOMIC_RELAXED, __HIP_MEMORY_SCOPE_AGENT);

        float    gm[4] = {-1.f, -1.f, -1.f, -1.f};
        unsigned gi[4] = {0u, 0u, 0u, 0u};
#pragma unroll
        for (int i = 0; i < 16; ++i) {
            float dx = __fsub_rn(px[i], cx);
            float dy = __fsub_rn(py[i], cy);
            float dz = __fsub_rn(pz[i], cz);
            float d  = __fadd_rn(__fadd_rn(__fmul_rn(dx,dx), __fmul_rn(dy,dy)), __fmul_rn(dz,dz));
            float nd = fminf(dd[i], d);
            dd[i] = nd;
            const int g = i >> 2;
            if (nd > gm[g]) gi[g] = (unsigned)(t + i*256);
            gm[g] = fmaxf(gm[g], nd);
        }
        bool c1 = gm[1] > gm[0]; float a0 = c1 ? gm[1] : gm[0]; unsigned b0 = c1 ? gi[1] : gi[0];
        bool c3 = gm[3] > gm[2]; float a1 = c3 ? gm[3] : gm[2]; unsigned b1 = c3 ? gi[3] : gi[2];
        bool cf = a1 > a0;       float am = cf ? a1 : a0;       unsigned bm = cf ? b1 : b0;
        u64 k = ((u64)__float_as_uint(am) << 32) | (u64)(unsigned)~bm;

        k = wave_red_u64<true>(k);

        const int buf = s & 1;
        if ((t & 63) == 63) s_ck[buf][t>>6] = k;
        __syncthreads();
        u64 k0 = s_ck[buf][0], k1 = s_ck[buf][1], k2 = s_ck[buf][2], k3 = s_ck[buf][3];
        float4 c0 = s_xyz[(int)~((unsigned)k0)];
        float4 c1v = s_xyz[(int)~((unsigned)k1)];
        float4 c2v = s_xyz[(int)~((unsigned)k2)];
        float4 c3v = s_xyz[(int)~((unsigned)k3)];
        bool m1 = k1 > k0; u64 ka = m1 ? k1 : k0; float4 ca = m1 ? c1v : c0;
        bool m3 = k3 > k2; u64 kb = m3 ? k3 : k2; float4 cb = m3 ? c3v : c2v;
        bool mf = kb > ka; u64 kw = mf ? kb : ka; float4 cw = mf ? cb : ca;
        far = (int)~((unsigned)kw);
        cx = cw.x; cy = cw.y; cz = cw.z;
    }
    __builtin_amdgcn_s_setprio(0);
}

// ---------------------------------------------------------------------------
// kNN role (round-5 verified body). Cold-polls fps_idx[bs] (sentinel -1,
// s_sleep(64) ~1.7us/poll), registers winners (myw), stores once at the end
// with relaxed agent atomics, then release-publishes knn_done[bs] after a
// block barrier (barrier's vmcnt(0) drains all waves' stores first).
// ---------------------------------------------------------------------------
__device__ __forceinline__ void knn_role(int n, const float* __restrict__ xyz,
                                         int* __restrict__ fps_idx,
                                         int* __restrict__ nbr_idx,
                                         int* __restrict__ knn_done, char* s_raw)
{
    u64 (*s_ck)[4] = (u64(*)[4])s_raw;
    int* s_ci      = (int*)(s_raw + 64);

    const int b  = n & 3;
    const int s  = n >> 2;
    const int bs = (b << 10) + s;
    const int t  = threadIdx.x;

    if (t == 0) {
        int v;
        while ((v = __hip_atomic_load(&fps_idx[bs], __ATOMIC_RELAXED, __HIP_MEMORY_SCOPE_AGENT)) < 0)
            __builtin_amdgcn_s_sleep(64);
        *s_ci = v;
    }
    __syncthreads();
    const int ci = *s_ci;

    const float* xb = xyz + (size_t)b * NPTS * 3;
    const float cx = xb[ci*3], cy = xb[ci*3+1], cz = xb[ci*3+2];
    const float sqc = __fadd_rn(__fadd_rn(__fmul_rn(cx,cx), __fmul_rn(cy,cy)), __fmul_rn(cz,cz));

    u64 key[16];
#pragma unroll
    for (int i = 0; i < 16; ++i) {
        int p = t + i * 256;
        float x = xb[p*3], y = xb[p*3+1], z = xb[p*3+2];
        float sqm = __fadd_rn(__fadd_rn(__fmul_rn(x,x), __fmul_rn(y,y)), __fmul_rn(z,z));
        float dot = __fadd_rn(__fadd_rn(__fmul_rn(cx,x), __fmul_rn(cy,y)), __fmul_rn(cz,z));
        float dv  = __fsub_rn(__fadd_rn(sqc, sqm), __fmul_rn(2.0f, dot));
        unsigned u = __float_as_uint(dv);
        u ^= (unsigned)(((int)u >> 31)) | 0x80000000u;   // order-monotonic for all floats
        key[i] = ((u64)u << 32) | (unsigned)p;
    }
    u64 kmin = key[0];
#pragma unroll
    for (int i = 1; i < 16; ++i) if (key[i] < kmin) kmin = key[i];

    int myw = 0;

    for (int kk = 0; kk < KNN; ++kk) {
        u64 k = wave_red_u64<false>(kmin);
        const int buf = kk & 1;
        if ((t & 63) == 63) s_ck[buf][t>>6] = k;
        __syncthreads();
        u64 k0 = s_ck[buf][0], k1 = s_ck[buf][1], k2 = s_ck[buf][2], k3 = s_ck[buf][3];
        if (k1 < k0) k0 = k1;
        if (k3 < k2) k2 = k3;
        if (k2 < k0) k0 = k2;
        unsigned w = (unsigned)k0;
        if (kk == t) myw = (int)w;
        if ((w & 255u) == (unsigned)t) {          // only the owner thread
#pragma unroll
            for (int i = 0; i < 16; ++i)
                if (w == (unsigned)(t + i*256)) key[i] = ~0ull;
            u64 m = key[0];
#pragma unroll
            for (int i = 1; i < 16; ++i) if (key[i] < m) m = key[i];
            kmin = m;
        }
    }
    if (t < KNN)
        __hip_atomic_store(&nbr_idx[bs*KNN + t], myw, __ATOMIC_RELAXED, __HIP_MEMORY_SCOPE_AGENT);
    __syncthreads();
    if (t == 0)
        __hip_atomic_store(&knn_done[bs], 1, __ATOMIC_RELEASE, __HIP_MEMORY_SCOPE_AGENT);
}

// ---------------------------------------------------------------------------
// Attention (verified math, unchanged): wave g owns center g.
// ---------------------------------------------------------------------------
template<int TYPE>
__device__ __forceinline__ void attn_t(
    int b, int bs0, int ci,
    const float* __restrict__ fea, const float* __restrict__ aux,
    const float* __restrict__ Mt, const float* __restrict__ Wvpt,
    float* __restrict__ outp,
    float (*s_cf)[CIN], float (*s_u)[DP], float (*s_fea)[KNN][DP],
    float (*s_sc)[KNN], float (*s_wf)[DP], const int (*s_nbr4)[KNN])
{
    const int t = threadIdx.x, g = t >> 6, l = t & 63;
    const int l31 = l & 31, h32 = l >> 5;

    if (l < 32) {
        float4 v = *(const float4*)&fea[((size_t)(b*NPTS + ci))*CIN + l*4];
        *(float4*)&s_cf[g][l*4] = v;
    }
#pragma unroll
    for (int it = 0; it < 16; ++it) {
        int kk = it*2 + h32;
        int j  = s_nbr4[g][kk];
        float4 v = *(const float4*)&fea[((size_t)(b*NPTS + j))*CIN + l31*4];
        *(float4*)&s_fea[g][kk][l31*4] = v;
    }
    if (l < KNN) {
        int j = s_nbr4[g][l];
        float pad[8];
        if (TYPE == 0 || TYPE == 3) {
#pragma unroll
            for (int i = 0; i < 3; ++i)
                pad[i] = aux[(size_t)(b*NPTS + j)*3 + i] - aux[(size_t)(b*NPTS + ci)*3 + i];
            pad[3]=pad[4]=pad[5]=pad[6]=pad[7]=0.f;
        } else if (TYPE == 1) {
            pad[0] = aux[(size_t)(b*NPTS + j)*2 + 0];
            pad[1] = aux[(size_t)(b*NPTS + j)*2 + 1];
            pad[2] = aux[(size_t)(b*NPTS + ci)*2 + 0];
            pad[3] = aux[(size_t)(b*NPTS + ci)*2 + 1];
            pad[4]=pad[5]=pad[6]=pad[7]=0.f;
        } else {
#pragma unroll
            for (int i = 0; i < 4; ++i) pad[i]   = aux[(size_t)(b*NPTS + j)*4 + i];
#pragma unroll
            for (int i = 0; i < 4; ++i) pad[4+i] = aux[(size_t)(b*NPTS + ci)*4 + i];
        }
#pragma unroll
        for (int i = 0; i < 8; ++i) s_fea[g][l][CIN+i] = pad[i];
    }
    __syncthreads();

#pragma unroll
    for (int j = 0; j < 3; ++j) {
        int d = l + 64*j;
        if (d < DP) {
            float acc = 0.f;
            for (int c = 0; c < CIN; c += 4) {
                float4 cf4 = *(const float4*)&s_cf[g][c];
                acc = fmaf(cf4.x, Mt[(size_t)(c+0)*DP + d], acc);
                acc = fmaf(cf4.y, Mt[(size_t)(c+1)*DP + d], acc);
                acc = fmaf(cf4.z, Mt[(size_t)(c+2)*DP + d], acc);
                acc = fmaf(cf4.w, Mt[(size_t)(c+3)*DP + d], acc);
            }
            s_u[g][d] = acc;
        }
    }
    __syncthreads();

#pragma unroll
    for (int it = 0; it < 16; ++it) {
        int kk = it*2 + h32;
        float acc = 0.f;
        for (int c = l31; c < DP/4; c += 32) {
            float4 f4 = *(const float4*)&s_fea[g][kk][c*4];
            float4 u4 = *(const float4*)&s_u[g][c*4];
            acc = fmaf(f4.x,u4.x,acc); acc = fmaf(f4.y,u4.y,acc);
            acc = fmaf(f4.z,u4.z,acc); acc = fmaf(f4.w,u4.w,acc);
        }
#pragma unroll
        for (int off = 16; off; off >>= 1) acc += __shfl_xor(acc, off);
        if (l31 == 0) s_sc[g][kk] = acc * 0.0625f;
    }
    __syncthreads();

    if (l < KNN) {
        float sc = s_sc[g][l];
        float m = sc;
#pragma unroll
        for (int off = 16; off; off >>= 1) m = fmaxf(m, __shfl_xor(m, off));
        float e = expf(sc - m);
        float ssum = e;
#pragma unroll
        for (int off = 16; off; off >>= 1) ssum += __shfl_xor(ssum, off);
        s_sc[g][l] = e / ssum;
    }
    __syncthreads();

    if (l < DP/4) {
        const int d0 = l*4;
        float w0=0.f, w1=0.f, w2=0.f, w3=0.f;
#pragma unroll
        for (int k4 = 0; k4 < KNN; k4 += 4) {
            float4 a  = *(const float4*)&s_sc[g][k4];
            float4 f0 = *(const float4*)&s_fea[g][k4+0][d0];
            float4 f1 = *(const float4*)&s_fea[g][k4+1][d0];
            float4 f2 = *(const float4*)&s_fea[g][k4+2][d0];
            float4 f3 = *(const float4*)&s_fea[g][k4+3][d0];
            w0=fmaf(a.x,f0.x,w0); w1=fmaf(a.x,f0.y,w1); w2=fmaf(a.x,f0.z,w2); w3=fmaf(a.x,f0.w,w3);
            w0=fmaf(a.y,f1.x,w0); w1=fmaf(a.y,f1.y,w1); w2=fmaf(a.y,f1.z,w2); w3=fmaf(a.y,f1.w,w3);
            w0=fmaf(a.z,f2.x,w0); w1=fmaf(a.z,f2.y,w1); w2=fmaf(a.z,f2.z,w2); w3=fmaf(a.z,f2.w,w3);
            w0=fmaf(a.w,f3.x,w0); w1=fmaf(a.w,f3.y,w1); w2=fmaf(a.w,f3.z,w2); w3=fmaf(a.w,f3.w,w3);
        }
        s_wf[g][d0+0]=w0; s_wf[g][d0+1]=w1; s_wf[g][d0+2]=w2; s_wf[g][d0+3]=w3;
    }
    __syncthreads();

    float o0=0.f, o1=0.f, o2=0.f, o3=0.f;
    for (int d4 = 0; d4 < DP/4; ++d4) {
        float4 wf0 = *(const float4*)&s_wf[0][d4*4];
        float4 wf1 = *(const float4*)&s_wf[1][d4*4];
        float4 wf2 = *(const float4*)&s_wf[2][d4*4];
        float4 wf3 = *(const float4*)&s_wf[3][d4*4];
        float v0 = Wvpt[(size_t)(d4*4+0)*CO + t];
        float v1 = Wvpt[(size_t)(d4*4+1)*CO + t];
        float v2 = Wvpt[(size_t)(d4*4+2)*CO + t];
        float v3 = Wvpt[(size_t)(d4*4+3)*CO + t];
        o0=fmaf(wf0.x,v0,o0); o0=fmaf(wf0.y,v1,o0); o0=fmaf(wf0.z,v2,o0); o0=fmaf(wf0.w,v3,o0);
        o1=fmaf(wf1.x,v0,o1); o1=fmaf(wf1.y,v1,o1); o1=fmaf(wf1.z,v2,o1); o1=fmaf(wf1.w,v3,o1);
        o2=fmaf(wf2.x,v0,o2); o2=fmaf(wf2.y,v1,o2); o2=fmaf(wf2.z,v2,o2); o2=fmaf(wf2.w,v3,o2);
        o3=fmaf(wf3.x,v0,o3); o3=fmaf(wf3.y,v1,o3); o3=fmaf(wf3.z,v2,o3); o3=fmaf(wf3.w,v3,o3);
    }
    outp[(size_t)(bs0+0)*CO + t] = o0;
    outp[(size_t)(bs0+1)*CO + t] = o1;
    outp[(size_t)(bs0+2)*CO + t] = o2;
    outp[(size_t)(bs0+3)*CO + t] = o3;
    __syncthreads();
}

__device__ __forceinline__ void attn_role(int a,
    const float* __restrict__ xyz, const float* __restrict__ mad,
    const float* __restrict__ adj, const float* __restrict__ pt,
    const float* __restrict__ mad_fea, const float* __restrict__ adj_fea,
    const float* __restrict__ pt_fea,  const float* __restrict__ cst_fea,
    const float* __restrict__ M, const float* __restrict__ Wvp,
    int* __restrict__ fps_idx, int* __restrict__ nbr_idx, int* __restrict__ knn_done,
    float* __restrict__ out, char* s_raw)
{
    float (*s_cf)[CIN]      = (float(*)[CIN])     (s_raw);          // 2048
    float (*s_u)[DP]        = (float(*)[DP])      (s_raw + 2048);   // 2176
    float (*s_fea)[KNN][DP] = (float(*)[KNN][DP]) (s_raw + 4224);   // 69632
    float (*s_sc)[KNN]      = (float(*)[KNN])     (s_raw + 73856);  // 512
    float (*s_wf)[DP]       = (float(*)[DP])      (s_raw + 74368);  // 2176
    int   (*s_nbr4)[KNN]    = (int(*)[KNN])       (s_raw + 76544);  // 512
    int   *s_ci4            = (int*)              (s_raw + 77056);  // 16

    const int b   = a & 3;
    const int bs0 = (b << 10) + ((a >> 2) << 2);
    const int t   = threadIdx.x;
    const int g   = t >> 6, l = t & 63;

    if (t < 4) {
        while (__hip_atomic_load(&knn_done[bs0 + t], __ATOMIC_ACQUIRE, __HIP_MEMORY_SCOPE_AGENT) == 0)
            __builtin_amdgcn_s_sleep(64);
        s_ci4[t] = __hip_atomic_load(&fps_idx[bs0 + t], __ATOMIC_RELAXED, __HIP_MEMORY_SCOPE_AGENT);
    }
    __syncthreads();
    if (t < 128)
        s_nbr4[t>>5][t&31] =
            __hip_atomic_load(&nbr_idx[(bs0 + (t>>5))*KNN + (t&31)], __ATOMIC_RELAXED, __HIP_MEMORY_SCOPE_AGENT);
    __syncthreads();
    const int ci = s_ci4[g];

    if (l < 3)             out[OFF_CXYZ + (bs0+g)*3 + l]      = xyz[(size_t)(b*NPTS+ci)*3 + l];
    if (l >= 4 && l < 7)   out[OFF_CMAD + (bs0+g)*3 + (l-4)]  = mad[(size_t)(b*NPTS+ci)*3 + (l-4)];
    if (l >= 8 && l < 10)  out[OFF_CADJ + (bs0+g)*2 + (l-8)]  = adj[(size_t)(b*NPTS+ci)*2 + (l-8)];
    if (l >= 12 && l < 16) out[OFF_CPT  + (bs0+g)*4 + (l-12)] = pt[(size_t)(b*NPTS+ci)*4 + (l-12)];

    attn_t<0>(b, bs0, ci, mad_fea, mad, M + 0*CIN*DP, Wvp + 0*DP*CO, out + OFF_OMAD,
              s_cf, s_u, s_fea, s_sc, s_wf, s_nbr4);
    attn_t<1>(b, bs0, ci, adj_fea, adj, M + 1*CIN*DP, Wvp + 1*DP*CO, out + OFF_OADJ,
              s_cf, s_u, s_fea, s_sc, s_wf, s_nbr4);
    attn_t<2>(b, bs0, ci, pt_fea,  pt,  M + 2*CIN*DP, Wvp + 2*DP*CO, out + OFF_OPT,
              s_cf, s_u, s_fea, s_sc, s_wf, s_nbr4);
    attn_t<3>(b, bs0, ci, cst_fea, xyz, M + 3*CIN*DP, Wvp + 3*DP*CO, out + OFF_OCST,
              s_cf, s_u, s_fea, s_sc, s_wf, s_nbr4);
}

// ---------------------------------------------------------------------------
// Mega kernel. Roles by ARRIVAL ticket (first 4 arrivals = FPS producers ->
// no dispatch-order assumption, no deadlock: knn depends only on resident
// FPS; 4:1 knn:attn interleave keeps retirement flowing so attn providers
// always launch). LDS 77.3KB -> 2 blocks/CU: workers run at 8 waves/CU
// (attn at its standalone occupancy), fixing round-1's worker starvation.
// ---------------------------------------------------------------------------
__global__ __launch_bounds__(256) void mega_kernel(
    const float* __restrict__ xyz, const float* __restrict__ mad,
    const float* __restrict__ adj, const float* __restrict__ pt,
    const float* __restrict__ mad_fea, const float* __restrict__ adj_fea,
    const float* __restrict__ pt_fea,  const float* __restrict__ cst_fea,
    const float* __restrict__ M, const float* __restrict__ Wvp,
    int* __restrict__ fps_idx, int* __restrict__ nbr_idx,
    int* __restrict__ knn_done, int* __restrict__ ticket,
    float* __restrict__ out)
{
    __shared__ __align__(16) char s_raw[77312];
    __shared__ int s_ticket;
    const int t = threadIdx.x;
    if (t == 0) s_ticket = atomicAdd(ticket, 1);
    __syncthreads();
    const int T = s_ticket;

    if (T < BATCH) {
        fps_role(T, xyz, fps_idx, s_raw);
        return;
    }
    const int u = T - BATCH;
    const int q = u / 5;
    const int r = u - q * 5;
    if (r < 4)
        knn_role(q*4 + r, xyz, fps_idx, nbr_idx, knn_done, s_raw);
    else
        attn_role(q, xyz, mad, adj, pt, mad_fea, adj_fea, pt_fea, cst_fea,
                  M, Wvp, fps_idx, nbr_idx, knn_done, out, s_raw);
}

extern "C" void kernel_launch(void* const* d_in, const int* in_sizes, int n_in,
                              void* d_out, int out_size, void* d_ws, size_t ws_size,
                              hipStream_t stream)
{
    const float* xyz     = (const float*)d_in[0];
    const float* mad     = (const float*)d_in[1];
    const float* adj     = (const float*)d_in[2];
    const float* pt      = (const float*)d_in[3];
    const float* mad_fea = (const float*)d_in[4];
    const float* adj_fea = (const float*)d_in[5];
    const float* pt_fea  = (const float*)d_in[6];
    const float* cst_fea = (const float*)d_in[7];
    const float* wq_mad  = (const float*)d_in[8];
    const float* wk_mad  = (const float*)d_in[9];
    const float* wv_mad  = (const float*)d_in[10];
    const float* wq_adj  = (const float*)d_in[11];
    const float* wk_adj  = (const float*)d_in[12];
    const float* wv_adj  = (const float*)d_in[13];
    const float* wq_pt   = (const float*)d_in[14];
    const float* wk_pt   = (const float*)d_in[15];
    const float* wv_pt   = (const float*)d_in[16];
    const float* wq_cst  = (const float*)d_in[17];
    const float* wk_cst  = (const float*)d_in[18];
    const float* wv_cst  = (const float*)d_in[19];
    float* out = (float*)d_out;

    int*   fps_idx  = (int*)d_ws;                      // 4096 ints (memset 0xFF -> -1)
    int*   knn_done = fps_idx + BATCH*NC;              // 4096 ints (memset 0)
    int*   ticket   = knn_done + BATCH*NC;             // 1 int + pad (memset 0)
    int*   nbr_idx  = ticket + 64;                     // 131072 ints
    float* M        = (float*)(nbr_idx + BATCH*NC*KNN);// 4*128*136 floats
    float* Wvp      = M + 4*CIN*DP;                    // 4*136*256 floats

    hipMemsetAsync(fps_idx, 0xFF, (size_t)BATCH*NC*sizeof(int), stream);
    hipMemsetAsync(knn_done, 0, (size_t)(BATCH*NC + 64)*sizeof(int), stream);

    prep_kernel<<<4*DP, 256, 0, stream>>>(
        wq_mad, wk_mad, wv_mad, wq_adj, wk_adj, wv_adj,
        wq_pt, wk_pt, wv_pt, wq_cst, wk_cst, wv_cst, M, Wvp);

    mega_kernel<<<BATCH + 5*(BATCH*NC/4), 256, 0, stream>>>(
        xyz, mad, adj, pt, mad_fea, adj_fea, pt_fea, cst_fea,
        M, Wvp, fps_idx, nbr_idx, knn_done, ticket, out);
}

// Round 7
// 986.197 us; speedup vs baseline: 1.4009x; 1.4009x over previous
//
#include <hip/hip_runtime.h>

#define BATCH 4
#define NPTS  4096
#define NC    1024
#define KNN   32
#define CIN   128
#define CO    256
#define DP    136   // padded feature dim (max over types); pad entries are exact zeros

// output layout (flat f32, reference return order)
#define OFF_CXYZ 0
#define OFF_CMAD (BATCH*NC*3)
#define OFF_CADJ (OFF_CMAD + BATCH*NC*3)
#define OFF_CPT  (OFF_CADJ + BATCH*NC*2)
#define OFF_OMAD (OFF_CPT  + BATCH*NC*4)
#define OFF_OADJ (OFF_OMAD + BATCH*NC*CO)
#define OFF_OPT  (OFF_OADJ + BATCH*NC*CO)
#define OFF_OCST (OFF_OPT  + BATCH*NC*CO)

typedef unsigned long long u64;

// ---------------------------------------------------------------------------
// u64 wave-64 reduce via DPP (VALU pipe). Result valid in lane 63.
// ---------------------------------------------------------------------------
template<bool MAXI>
__device__ __forceinline__ u64 wave_red_u64(u64 k)
{
    const int oldv = MAXI ? 0 : -1;
#define DPP_STEP(C)                                                              \
    {                                                                            \
        unsigned plo = (unsigned)__builtin_amdgcn_update_dpp(oldv, (int)(unsigned)k,        C, 0xf, 0xf, false); \
        unsigned phi = (unsigned)__builtin_amdgcn_update_dpp(oldv, (int)(unsigned)(k>>32),  C, 0xf, 0xf, false); \
        u64 p = ((u64)phi << 32) | plo;                                          \
        if (MAXI ? (p > k) : (p < k)) k = p;                                     \
    }
    DPP_STEP(0x111) DPP_STEP(0x112) DPP_STEP(0x114)
    DPP_STEP(0x118) DPP_STEP(0x142) DPP_STEP(0x143)
#undef DPP_STEP
    return k;
}

// ---------------------------------------------------------------------------
// Fused kernel: blocks 0..3 run FPS (round-5 verified: LDS-buffered winner
// publishes, coalesced dump after the loop); blocks 4..547 precompute
// M[type] = Wq·Wk^T (zero-padded) and the zero-padded Wvp.
// ---------------------------------------------------------------------------
__global__ __launch_bounds__(256) void fps_prep_kernel(
    const float* __restrict__ xyz, int* __restrict__ fps_idx,
    const float* __restrict__ wq_mad, const float* __restrict__ wk_mad, const float* __restrict__ wv_mad,
    const float* __restrict__ wq_adj, const float* __restrict__ wk_adj, const float* __restrict__ wv_adj,
    const float* __restrict__ wq_pt,  const float* __restrict__ wk_pt,  const float* __restrict__ wv_pt,
    const float* __restrict__ wq_cst, const float* __restrict__ wk_cst, const float* __restrict__ wv_cst,
    float* __restrict__ M, float* __restrict__ Wvp)
{
    __shared__ float4 s_xyz[NPTS];          // 64 KB (prep reuses as scratch)
    __shared__ u64    s_ck[2][4];
    __shared__ int    s_far[NC];            // 4 KB winner buffer
    const int t = threadIdx.x;

    if (blockIdx.x >= BATCH) {
        // ---------------- prep path ----------------
        const int r    = blockIdx.x - BATCH;   // 0..4*DP-1
        const int type = r / DP;
        const int row  = r - type * DP;
        const float* wq; const float* wk; const float* wv; int D;
        if (type == 0)      { wq=wq_mad; wk=wk_mad; wv=wv_mad; D=131; }
        else if (type == 1) { wq=wq_adj; wk=wk_adj; wv=wv_adj; D=132; }
        else if (type == 2) { wq=wq_pt;  wk=wk_pt;  wv=wv_pt;  D=136; }
        else                { wq=wq_cst; wk=wk_cst; wv=wv_cst; D=131; }

        // zero-padded Wvp row
        Wvp[((size_t)type*DP + row)*CO + t] = (row < D) ? wv[(size_t)row*CO + t] : 0.f;

        // M[row][d] = sum_h Wq[row][h] * Wk[d][h]   (zero for d >= D)
        if (row < CIN) {
            float* sq = (float*)s_xyz;
            sq[t] = wq[(size_t)row*CO + t];
            __syncthreads();
            if (t < DP) {
                float acc = 0.f;
                if (t < D) {
                    const float* wkr = wk + (size_t)t * CO;
                    for (int h = 0; h < CO; h += 4) {
                        float4 a = *(const float4*)&wkr[h];
                        float4 b4 = *(const float4*)&sq[h];
                        acc = fmaf(a.x,b4.x,acc); acc = fmaf(a.y,b4.y,acc);
                        acc = fmaf(a.z,b4.z,acc); acc = fmaf(a.w,b4.w,acc);
                    }
                }
                M[((size_t)type*CIN + row)*DP + t] = acc;
            }
        }
        return;
    }

    // ---------------- FPS path (round-5 verified) ----------------
    const int b = blockIdx.x;
    const float* xb = xyz + (size_t)b * NPTS * 3;

    float px[16], py[16], pz[16], dd[16];
#pragma unroll
    for (int i = 0; i < 16; ++i) {
        int p = t + i * 256;
        px[i] = xb[p*3+0]; py[i] = xb[p*3+1]; pz[i] = xb[p*3+2];
        s_xyz[p] = make_float4(px[i], py[i], pz[i], 0.f);
        dd[i] = 1e10f;
    }
    __syncthreads();

    int far = 0;
    float cx = xb[0], cy = xb[1], cz = xb[2];
    for (int s = 0; s < NC; ++s) {
        if (t == 0) s_far[s] = far;           // LDS, not global: no vmcnt drain

        float    gm[4] = {-1.f, -1.f, -1.f, -1.f};
        unsigned gi[4] = {0u, 0u, 0u, 0u};
#pragma unroll
        for (int i = 0; i < 16; ++i) {
            float dx = __fsub_rn(px[i], cx);
            float dy = __fsub_rn(py[i], cy);
            float dz = __fsub_rn(pz[i], cz);
            float d  = __fadd_rn(__fadd_rn(__fmul_rn(dx,dx), __fmul_rn(dy,dy)), __fmul_rn(dz,dz));
            float nd = fminf(dd[i], d);
            dd[i] = nd;
            const int g = i >> 2;
            if (nd > gm[g]) gi[g] = (unsigned)(t + i*256);
            gm[g] = fmaxf(gm[g], nd);
        }
        bool c1 = gm[1] > gm[0]; float a0 = c1 ? gm[1] : gm[0]; unsigned b0 = c1 ? gi[1] : gi[0];
        bool c3 = gm[3] > gm[2]; float a1 = c3 ? gm[3] : gm[2]; unsigned b1 = c3 ? gi[3] : gi[2];
        bool cf = a1 > a0;       float am = cf ? a1 : a0;       unsigned bm = cf ? b1 : b0;
        u64 k = ((u64)__float_as_uint(am) << 32) | (u64)(unsigned)~bm;

        k = wave_red_u64<true>(k);

        const int buf = s & 1;
        if ((t & 63) == 63) s_ck[buf][t>>6] = k;
        __syncthreads();
        u64 k0 = s_ck[buf][0], k1 = s_ck[buf][1], k2 = s_ck[buf][2], k3 = s_ck[buf][3];
        float4 c0 = s_xyz[(int)~((unsigned)k0)];
        float4 c1v = s_xyz[(int)~((unsigned)k1)];
        float4 c2v = s_xyz[(int)~((unsigned)k2)];
        float4 c3v = s_xyz[(int)~((unsigned)k3)];
        bool m1 = k1 > k0; u64 ka = m1 ? k1 : k0; float4 ca = m1 ? c1v : c0;
        bool m3 = k3 > k2; u64 kb = m3 ? k3 : k2; float4 cb = m3 ? c3v : c2v;
        bool mf = kb > ka; u64 kw = mf ? kb : ka; float4 cw = mf ? cb : ca;
        far = (int)~((unsigned)kw);
        cx = cw.x; cy = cw.y; cz = cw.z;
    }

    __syncthreads();
#pragma unroll
    for (int j = 0; j < 4; ++j)
        fps_idx[b*NC + t + j*256] = s_far[t + j*256];
}

// ---------------------------------------------------------------------------
// kNN with tournament caching (round-5 verified: winners registered, one
// store after the loop).
// ---------------------------------------------------------------------------
__global__ __launch_bounds__(256) void knn_kernel(const float* __restrict__ xyz,
                                                  const int* __restrict__ fps_idx,
                                                  int* __restrict__ nbr_idx)
{
    const int bs = blockIdx.x;
    const int b  = bs >> 10;
    const int t  = threadIdx.x;
    const float* xb = xyz + (size_t)b * NPTS * 3;
    const int ci = fps_idx[bs];
    const float cx = xb[ci*3], cy = xb[ci*3+1], cz = xb[ci*3+2];
    const float sqc = __fadd_rn(__fadd_rn(__fmul_rn(cx,cx), __fmul_rn(cy,cy)), __fmul_rn(cz,cz));

    u64 key[16];
#pragma unroll
    for (int i = 0; i < 16; ++i) {
        int p = t + i * 256;
        float x = xb[p*3], y = xb[p*3+1], z = xb[p*3+2];
        float sqm = __fadd_rn(__fadd_rn(__fmul_rn(x,x), __fmul_rn(y,y)), __fmul_rn(z,z));
        float dot = __fadd_rn(__fadd_rn(__fmul_rn(cx,x), __fmul_rn(cy,y)), __fmul_rn(cz,z));
        float dv  = __fsub_rn(__fadd_rn(sqc, sqm), __fmul_rn(2.0f, dot));
        unsigned u = __float_as_uint(dv);
        u ^= (unsigned)(((int)u >> 31)) | 0x80000000u;   // order-monotonic for all floats
        key[i] = ((u64)u << 32) | (unsigned)p;
    }
    u64 kmin = key[0];
#pragma unroll
    for (int i = 1; i < 16; ++i) if (key[i] < kmin) kmin = key[i];

    __shared__ u64 s_ck[2][4];

    int myw = 0;

    for (int kk = 0; kk < KNN; ++kk) {
        u64 k = wave_red_u64<false>(kmin);
        const int buf = kk & 1;
        if ((t & 63) == 63) s_ck[buf][t>>6] = k;
        __syncthreads();
        u64 k0 = s_ck[buf][0], k1 = s_ck[buf][1], k2 = s_ck[buf][2], k3 = s_ck[buf][3];
        if (k1 < k0) k0 = k1;
        if (k3 < k2) k2 = k3;
        if (k2 < k0) k0 = k2;
        unsigned w = (unsigned)k0;
        if (kk == t) myw = (int)w;
        if ((w & 255u) == (unsigned)t) {          // only the owner thread
#pragma unroll
            for (int i = 0; i < 16; ++i)
                if (w == (unsigned)(t + i*256)) key[i] = ~0ull;
            u64 m = key[0];
#pragma unroll
            for (int i = 1; i < 16; ++i) if (key[i] < m) m = key[i];
            kmin = m;
        }
    }
    if (t < KNN) nbr_idx[bs*KNN + t] = myw;
}

// ---------------------------------------------------------------------------
// Attention (verified math). TYPE-SPLIT: each block handles ONE (center-
// group, type) pair -> barriers per block 24 -> 6, per-block M/Wvp traffic
// 4x smaller, 4x more independent blocks so phases of different blocks
// interleave (latency hiding across blocks instead of serial types within).
// ---------------------------------------------------------------------------
template<int TYPE>
__device__ __forceinline__ void attn_t(
    int b, int bs0, int ci,
    const float* __restrict__ fea, const float* __restrict__ aux,
    const float* __restrict__ Mt, const float* __restrict__ Wvpt,
    float* __restrict__ outp,
    float (*s_cf)[CIN], float (*s_u)[DP], float (*s_fea)[KNN][DP],
    float (*s_sc)[KNN], float (*s_wf)[DP], const int (*s_nbr4)[KNN])
{
    const int t = threadIdx.x, g = t >> 6, l = t & 63;
    const int l31 = l & 31, h32 = l >> 5;

    // ---- stage (wave-private to center g) ----
    if (l < 32) {
        float4 v = *(const float4*)&fea[((size_t)(b*NPTS + ci))*CIN + l*4];
        *(float4*)&s_cf[g][l*4] = v;
    }
#pragma unroll
    for (int it = 0; it < 16; ++it) {
        int kk = it*2 + h32;
        int j  = s_nbr4[g][kk];
        float4 v = *(const float4*)&fea[((size_t)(b*NPTS + j))*CIN + l31*4];
        *(float4*)&s_fea[g][kk][l31*4] = v;
    }
    if (l < KNN) {
        int j = s_nbr4[g][l];
        float pad[8];
        if (TYPE == 0 || TYPE == 3) {
#pragma unroll
            for (int i = 0; i < 3; ++i)
                pad[i] = aux[(size_t)(b*NPTS + j)*3 + i] - aux[(size_t)(b*NPTS + ci)*3 + i];
            pad[3]=pad[4]=pad[5]=pad[6]=pad[7]=0.f;
        } else if (TYPE == 1) {
            pad[0] = aux[(size_t)(b*NPTS + j)*2 + 0];
            pad[1] = aux[(size_t)(b*NPTS + j)*2 + 1];
            pad[2] = aux[(size_t)(b*NPTS + ci)*2 + 0];
            pad[3] = aux[(size_t)(b*NPTS + ci)*2 + 1];
            pad[4]=pad[5]=pad[6]=pad[7]=0.f;
        } else {
#pragma unroll
            for (int i = 0; i < 4; ++i) pad[i]   = aux[(size_t)(b*NPTS + j)*4 + i];
#pragma unroll
            for (int i = 0; i < 4; ++i) pad[4+i] = aux[(size_t)(b*NPTS + ci)*4 + i];
        }
#pragma unroll
        for (int i = 0; i < 8; ++i) s_fea[g][l][CIN+i] = pad[i];
    }
    __syncthreads();

    // ---- u[g][d] = sum_c cf[g][c] * M[c][d]  (M coalesced, cf via b128) ----
#pragma unroll
    for (int j = 0; j < 3; ++j) {
        int d = l + 64*j;
        if (d < DP) {
            float acc = 0.f;
            for (int c = 0; c < CIN; c += 4) {
                float4 cf4 = *(const float4*)&s_cf[g][c];
                acc = fmaf(cf4.x, Mt[(size_t)(c+0)*DP + d], acc);
                acc = fmaf(cf4.y, Mt[(size_t)(c+1)*DP + d], acc);
                acc = fmaf(cf4.z, Mt[(size_t)(c+2)*DP + d], acc);
                acc = fmaf(cf4.w, Mt[(size_t)(c+3)*DP + d], acc);
            }
            s_u[g][d] = acc;
        }
    }
    __syncthreads();

    // ---- scores[g][kk] = (u[g] . fea[g][kk]) / 16  (two dots per wave) ----
#pragma unroll
    for (int it = 0; it < 16; ++it) {
        int kk = it*2 + h32;
        float acc = 0.f;
        for (int c = l31; c < DP/4; c += 32) {
            float4 f4 = *(const float4*)&s_fea[g][kk][c*4];
            float4 u4 = *(const float4*)&s_u[g][c*4];
            acc = fmaf(f4.x,u4.x,acc); acc = fmaf(f4.y,u4.y,acc);
            acc = fmaf(f4.z,u4.z,acc); acc = fmaf(f4.w,u4.w,acc);
        }
#pragma unroll
        for (int off = 16; off; off >>= 1) acc += __shfl_xor(acc, off);
        if (l31 == 0) s_sc[g][kk] = acc * 0.0625f;
    }
    __syncthreads();

    // ---- softmax over 32 (lanes 0..31 of wave g) ----
    if (l < KNN) {
        float sc = s_sc[g][l];
        float m = sc;
#pragma unroll
        for (int off = 16; off; off >>= 1) m = fmaxf(m, __shfl_xor(m, off));
        float e = expf(sc - m);
        float ssum = e;
#pragma unroll
        for (int off = 16; off; off >>= 1) ssum += __shfl_xor(ssum, off);
        s_sc[g][l] = e / ssum;
    }
    __syncthreads();

    // ---- wfea[g][d] = sum_k attn[g][k] * fea[g][k][d]  (f4 chunks) ----
    if (l < DP/4) {
        const int d0 = l*4;
        float w0=0.f, w1=0.f, w2=0.f, w3=0.f;
#pragma unroll
        for (int k4 = 0; k4 < KNN; k4 += 4) {
            float4 a  = *(const float4*)&s_sc[g][k4];
            float4 f0 = *(const float4*)&s_fea[g][k4+0][d0];
            float4 f1 = *(const float4*)&s_fea[g][k4+1][d0];
            float4 f2 = *(const float4*)&s_fea[g][k4+2][d0];
            float4 f3 = *(const float4*)&s_fea[g][k4+3][d0];
            w0=fmaf(a.x,f0.x,w0); w1=fmaf(a.x,f0.y,w1); w2=fmaf(a.x,f0.z,w2); w3=fmaf(a.x,f0.w,w3);
            w0=fmaf(a.y,f1.x,w0); w1=fmaf(a.y,f1.y,w1); w2=fmaf(a.y,f1.z,w2); w3=fmaf(a.y,f1.w,w3);
            w0=fmaf(a.z,f2.x,w0); w1=fmaf(a.z,f2.y,w1); w2=fmaf(a.z,f2.z,w2); w3=fmaf(a.z,f2.w,w3);
            w0=fmaf(a.w,f3.x,w0); w1=fmaf(a.w,f3.y,w1); w2=fmaf(a.w,f3.z,w2); w3=fmaf(a.w,f3.w,w3);
        }
        s_wf[g][d0+0]=w0; s_wf[g][d0+1]=w1; s_wf[g][d0+2]=w2; s_wf[g][d0+3]=w3;
    }
    __syncthreads();

    // ---- o[g][h=t] = sum_d wf[g][d] * Wvp[d][h]  (cross-wave, coalesced) ----
    float o0=0.f, o1=0.f, o2=0.f, o3=0.f;
    for (int d4 = 0; d4 < DP/4; ++d4) {
        float4 wf0 = *(const float4*)&s_wf[0][d4*4];
        float4 wf1 = *(const float4*)&s_wf[1][d4*4];
        float4 wf2 = *(const float4*)&s_wf[2][d4*4];
        float4 wf3 = *(const float4*)&s_wf[3][d4*4];
        float v0 = Wvpt[(size_t)(d4*4+0)*CO + t];
        float v1 = Wvpt[(size_t)(d4*4+1)*CO + t];
        float v2 = Wvpt[(size_t)(d4*4+2)*CO + t];
        float v3 = Wvpt[(size_t)(d4*4+3)*CO + t];
        o0=fmaf(wf0.x,v0,o0); o0=fmaf(wf0.y,v1,o0); o0=fmaf(wf0.z,v2,o0); o0=fmaf(wf0.w,v3,o0);
        o1=fmaf(wf1.x,v0,o1); o1=fmaf(wf1.y,v1,o1); o1=fmaf(wf1.z,v2,o1); o1=fmaf(wf1.w,v3,o1);
        o2=fmaf(wf2.x,v0,o2); o2=fmaf(wf2.y,v1,o2); o2=fmaf(wf2.z,v2,o2); o2=fmaf(wf2.w,v3,o2);
        o3=fmaf(wf3.x,v0,o3); o3=fmaf(wf3.y,v1,o3); o3=fmaf(wf3.z,v2,o3); o3=fmaf(wf3.w,v3,o3);
    }
    outp[(size_t)(bs0+0)*CO + t] = o0;
    outp[(size_t)(bs0+1)*CO + t] = o1;
    outp[(size_t)(bs0+2)*CO + t] = o2;
    outp[(size_t)(bs0+3)*CO + t] = o3;
}

__global__ __launch_bounds__(256) void attn_kernel(
    const float* __restrict__ xyz, const float* __restrict__ mad,
    const float* __restrict__ adj, const float* __restrict__ pt,
    const float* __restrict__ mad_fea, const float* __restrict__ adj_fea,
    const float* __restrict__ pt_fea,  const float* __restrict__ cst_fea,
    const float* __restrict__ M, const float* __restrict__ Wvp,
    const int* __restrict__ fps_idx, const int* __restrict__ nbr_idx,
    float* __restrict__ out)
{
    __shared__ float s_cf[4][CIN];
    __shared__ float s_u[4][DP];
    __shared__ float s_fea[4][KNN][DP];
    __shared__ float s_sc[4][KNN];
    __shared__ float s_wf[4][DP];
    __shared__ int   s_nbr4[4][KNN];
    __shared__ int   s_ci4[4];

    const int tp  = blockIdx.x >> 10;          // type 0..3 (type-major)
    const int cg  = blockIdx.x & 1023;         // center-group
    const int bs0 = cg * 4;
    const int b   = bs0 >> 10;
    const int t   = threadIdx.x;
    const int g   = t >> 6, l = t & 63;

    if (t < 4) s_ci4[t] = fps_idx[bs0 + t];
    if (t < 128) s_nbr4[t>>5][t&31] = nbr_idx[(bs0 + (t>>5))*KNN + (t&31)];
    __syncthreads();
    const int ci = s_ci4[g];

    if (tp == 0) {
        // small per-center outputs written once (type-0 blocks only)
        if (l < 3)             out[OFF_CXYZ + (bs0+g)*3 + l]      = xyz[(size_t)(b*NPTS+ci)*3 + l];
        if (l >= 4 && l < 7)   out[OFF_CMAD + (bs0+g)*3 + (l-4)]  = mad[(size_t)(b*NPTS+ci)*3 + (l-4)];
        if (l >= 8 && l < 10)  out[OFF_CADJ + (bs0+g)*2 + (l-8)]  = adj[(size_t)(b*NPTS+ci)*2 + (l-8)];
        if (l >= 12 && l < 16) out[OFF_CPT  + (bs0+g)*4 + (l-12)] = pt[(size_t)(b*NPTS+ci)*4 + (l-12)];
        attn_t<0>(b, bs0, ci, mad_fea, mad, M + 0*CIN*DP, Wvp + 0*DP*CO, out + OFF_OMAD,
                  s_cf, s_u, s_fea, s_sc, s_wf, s_nbr4);
    } else if (tp == 1) {
        attn_t<1>(b, bs0, ci, adj_fea, adj, M + 1*CIN*DP, Wvp + 1*DP*CO, out + OFF_OADJ,
                  s_cf, s_u, s_fea, s_sc, s_wf, s_nbr4);
    } else if (tp == 2) {
        attn_t<2>(b, bs0, ci, pt_fea,  pt,  M + 2*CIN*DP, Wvp + 2*DP*CO, out + OFF_OPT,
                  s_cf, s_u, s_fea, s_sc, s_wf, s_nbr4);
    } else {
        attn_t<3>(b, bs0, ci, cst_fea, xyz, M + 3*CIN*DP, Wvp + 3*DP*CO, out + OFF_OCST,
                  s_cf, s_u, s_fea, s_sc, s_wf, s_nbr4);
    }
}

extern "C" void kernel_launch(void* const* d_in, const int* in_sizes, int n_in,
                              void* d_out, int out_size, void* d_ws, size_t ws_size,
                              hipStream_t stream)
{
    const float* xyz     = (const float*)d_in[0];
    const float* mad     = (const float*)d_in[1];
    const float* adj     = (const float*)d_in[2];
    const float* pt      = (const float*)d_in[3];
    const float* mad_fea = (const float*)d_in[4];
    const float* adj_fea = (const float*)d_in[5];
    const float* pt_fea  = (const float*)d_in[6];
    const float* cst_fea = (const float*)d_in[7];
    const float* wq_mad  = (const float*)d_in[8];
    const float* wk_mad  = (const float*)d_in[9];
    const float* wv_mad  = (const float*)d_in[10];
    const float* wq_adj  = (const float*)d_in[11];
    const float* wk_adj  = (const float*)d_in[12];
    const float* wv_adj  = (const float*)d_in[13];
    const float* wq_pt   = (const float*)d_in[14];
    const float* wk_pt   = (const float*)d_in[15];
    const float* wv_pt   = (const float*)d_in[16];
    const float* wq_cst  = (const float*)d_in[17];
    const float* wk_cst  = (const float*)d_in[18];
    const float* wv_cst  = (const float*)d_in[19];
    float* out = (float*)d_out;

    int*   fps_idx = (int*)d_ws;                      // 4096 ints
    int*   nbr_idx = fps_idx + BATCH*NC;              // 131072 ints
    float* M       = (float*)(nbr_idx + BATCH*NC*KNN);// 4*128*136 floats
    float* Wvp     = M + 4*CIN*DP;                    // 4*136*256 floats

    fps_prep_kernel<<<BATCH + 4*DP, 256, 0, stream>>>(xyz, fps_idx,
        wq_mad, wk_mad, wv_mad, wq_adj, wk_adj, wv_adj,
        wq_pt, wk_pt, wv_pt, wq_cst, wk_cst, wv_cst, M, Wvp);
    knn_kernel<<<BATCH*NC, 256, 0, stream>>>(xyz, fps_idx, nbr_idx);
    attn_kernel<<<4*BATCH*NC/4, 256, 0, stream>>>(xyz, mad, adj, pt,
        mad_fea, adj_fea, pt_fea, cst_fea, M, Wvp, fps_idx, nbr_idx, out);
}